// Round 18
// baseline (173.667 us; speedup 1.0000x reference)
//
#include <hip/hip_runtime.h>
#include <hip/hip_bf16.h>

#define NNODES 8192
#define EMB    1024
#define HID    256
#define MAXDEG 128
#define SPLIT1 24      // 1-hop edges in slots [0,24); 2-hop (B^2) in [24,128)
#define MAXD2  104

typedef float f32x4 __attribute__((ext_vector_type(4)));
typedef short bf16x8v __attribute__((ext_vector_type(8)));
typedef unsigned short u16x4 __attribute__((ext_vector_type(4)));
typedef unsigned short u16x8 __attribute__((ext_vector_type(8)));

static __device__ __forceinline__ unsigned short f2bf(float f) {
  union { float f; unsigned int u; } x; x.f = f;
  unsigned int r = (x.u + 0x7fffu + ((x.u >> 16) & 1u)) >> 16;
  return (unsigned short)r;
}
static __device__ __forceinline__ float bf2f(unsigned short u) {
  union { unsigned int u; float f; } x; x.u = ((unsigned int)u) << 16;
  return x.f;
}

// ---------------------------------------------------------------------------
// Prep: Wt[n][k] = bf16(W[k][n]).  (R15 verbatim)
// ---------------------------------------------------------------------------
__global__ __launch_bounds__(256) void prep_wt(const float* __restrict__ W,
                                               unsigned short* __restrict__ Wt) {
  __shared__ float lds[64 * 65];
  int k0 = (blockIdx.x >> 2) * 64;
  int n0 = (blockIdx.x & 3) * 64;
  int t = threadIdx.x;
#pragma unroll
  for (int p = 0; p < 4; p++) {
    int k = p * 16 + (t >> 4);
    int c4 = (t & 15) * 4;
    float4 v = *(const float4*)&W[(size_t)(k0 + k) * HID + n0 + c4];
    lds[k * 65 + c4 + 0] = v.x; lds[k * 65 + c4 + 1] = v.y;
    lds[k * 65 + c4 + 2] = v.z; lds[k * 65 + c4 + 3] = v.w;
  }
  __syncthreads();
  int n = t >> 2, kq = t & 3;
  u16x8 o0, o1;
#pragma unroll
  for (int i = 0; i < 8; i++) o0[i] = f2bf(lds[(kq * 16 + i) * 65 + n]);
#pragma unroll
  for (int i = 0; i < 8; i++) o1[i] = f2bf(lds[(kq * 16 + 8 + i) * 65 + n]);
  unsigned short* dst = &Wt[(size_t)(n0 + n) * EMB + k0 + kq * 16];
  *(u16x8*)(dst) = o0;
  *(u16x8*)(dst + 8) = o1;
}

// ---------------------------------------------------------------------------
// Fused (R15 + sval + 1-hop clamp at SPLIT1): blocks [0,256) = GEMM;
// blocks [256, 256+8192) = extract with 8 batched nontemporal loads.
// ---------------------------------------------------------------------------
#define GEMM_BLOCKS 256

__global__ __launch_bounds__(256) void fused_extract_gemm(
    const float* __restrict__ X, const unsigned short* __restrict__ Wt,
    const float* __restrict__ bias, const float* __restrict__ adj,
    unsigned short* __restrict__ hb0, float* __restrict__ dinv,
    int* __restrict__ nnz, int* __restrict__ cols, float* __restrict__ vals,
    float* __restrict__ sval) {
  __shared__ char smem[24 * 1024 + 64];
  int t = threadIdx.x;

  if (blockIdx.x >= GEMM_BLOCKS) {
    // ---------------- extract path ----------------
    int row = blockIdx.x - GEMM_BLOCKS;
    int* s_cnt = (int*)smem;
    float* s_part = (float*)(smem + 16);
    if (t == 0) *s_cnt = 0;
    __syncthreads();
    const f32x4* arow = (const f32x4*)(adj + (size_t)row * NNODES);
    int base = row * MAXDEG;

    f32x4 v[8];
#pragma unroll
    for (int i = 0; i < 8; i++)
      v[i] = __builtin_nontemporal_load(arow + i * 256 + t);

    float sum = 0.f;
#pragma unroll
    for (int i = 0; i < 8; i++) {
      sum += v[i].x + v[i].y + v[i].z + v[i].w;
      int j0 = (i * 256 + t) * 4;
#pragma unroll
      for (int e = 0; e < 4; e++) {
        float f = v[i][e];
        if (f != 0.f) {
          int col = j0 + e;
          if (col == row) sval[row] = f;
          int p = atomicAdd(s_cnt, 1);
          if (p < SPLIT1) { cols[base + p] = col; vals[base + p] = f; }
        }
      }
    }
    for (int off = 32; off > 0; off >>= 1) sum += __shfl_down(sum, off, 64);
    int wave = t >> 6;
    if ((t & 63) == 0) s_part[wave] = sum;
    __syncthreads();
    if (t == 0) {
      float tot = s_part[0] + s_part[1] + s_part[2] + s_part[3];
      dinv[row] = rsqrtf(tot);
      int c = *s_cnt;
      nnz[row] = (c > SPLIT1) ? SPLIT1 : c;
    }
    return;
  }

  // ---------------- GEMM path (R15 verbatim) ----------------
  unsigned short* As = (unsigned short*)smem;               // [128][64] bf16
  unsigned short* Bs = (unsigned short*)(smem + 16 * 1024); // [64][64] bf16 (B^T)
  int mb = blockIdx.x >> 2, nb = blockIdx.x & 3;
  int m0 = mb * 128, n0 = nb * 64;
  int w = t >> 6, l = t & 63;

  f32x4 acc[2][4] = {};

  for (int kt = 0; kt < EMB; kt += 64) {
    __syncthreads();
    {
      int c4 = t & 15;
#pragma unroll
      for (int rr = 0; rr < 8; rr++) {
        int row = rr * 16 + (t >> 4);
        float4 v = *(const float4*)&X[(size_t)(m0 + row) * EMB + kt + c4 * 4];
        u16x4 pk = {f2bf(v.x), f2bf(v.y), f2bf(v.z), f2bf(v.w)};
        int slot = ((c4 >> 1) + (row >> 1)) & 7;
        *(u16x4*)&As[row * 64 + slot * 8 + (c4 & 1) * 4] = pk;
      }
    }
    {
      int n = t >> 2, q = t & 3;
      const unsigned short* src = &Wt[(size_t)(n0 + n) * EMB + kt + q * 16];
#pragma unroll
      for (int e = 0; e < 2; e++) {
        u16x8 v = *(const u16x8*)(src + e * 8);
        int slot = ((q * 2 + e) + (n >> 1)) & 7;
        *(u16x8*)&Bs[n * 64 + slot * 8] = v;
      }
    }
    __syncthreads();
#pragma unroll
    for (int ks = 0; ks < 2; ks++) {
      bf16x8v a[2], b[4];
#pragma unroll
      for (int mf = 0; mf < 2; mf++) {
        int row = w * 32 + mf * 16 + (l & 15);
        int slot = ((ks * 4 + (l >> 4)) + (row >> 1)) & 7;
        a[mf] = *(bf16x8v*)&As[row * 64 + slot * 8];
      }
#pragma unroll
      for (int nf = 0; nf < 4; nf++) {
        int rowB = nf * 16 + (l & 15);
        int slot = ((ks * 4 + (l >> 4)) + (rowB >> 1)) & 7;
        b[nf] = *(bf16x8v*)&Bs[rowB * 64 + slot * 8];
      }
#pragma unroll
      for (int mf = 0; mf < 2; mf++)
#pragma unroll
        for (int nf = 0; nf < 4; nf++)
          acc[mf][nf] = __builtin_amdgcn_mfma_f32_16x16x32_bf16(a[mf], b[nf], acc[mf][nf], 0, 0, 0);
    }
  }
#pragma unroll
  for (int mf = 0; mf < 2; mf++)
#pragma unroll
    for (int nf = 0; nf < 4; nf++) {
      int r0 = m0 + w * 32 + mf * 16 + (l >> 4) * 4;
      int cc = n0 + nf * 16 + (l & 15);
      float bv = bias[cc];
#pragma unroll
      for (int r = 0; r < 4; r++)
        hb0[(size_t)(r0 + r) * HID + cc] = f2bf(fmaxf(acc[mf][nf][r] + bv, 0.f));
    }
}

// ---------------------------------------------------------------------------
// ggbuild: blocks [0,2048) compute gg = 0.2*B*h0 + 0.2*h0 (wave/row, bf16);
// blocks [2048, 2048+32) build the B^2 CSR in-place (thread/row):
//   self: b_ii^2; child k: b_ik(b_ii+b_kk); grandchild g: b_ik*b_kg
// written to slots [SPLIT1, 128) of cols/vals (reads only [0,SPLIT1) of
// other rows -> race-free).  b_ij = 0.8*dinv_i*val_ij*dinv_j.
// ---------------------------------------------------------------------------
#define GG_BLOCKS (NNODES / 4)

__global__ __launch_bounds__(256) void ggbuild(
    const unsigned short* __restrict__ hb0, unsigned short* __restrict__ hbg,
    const float* __restrict__ dinv, const float* __restrict__ sval,
    const int* __restrict__ nnz, int* __restrict__ cols,
    float* __restrict__ vals, int* __restrict__ nnz2) {
  int t = threadIdx.x;

  if (blockIdx.x >= GG_BLOCKS) {
    // ---------------- build2: one thread per row ----------------
    int i = (blockIdx.x - GG_BLOCKS) * 256 + t;
    float di = dinv[i];
    float bii = 0.8f * di * di * sval[i];
    int n = nnz[i];
    int ib = i * MAXDEG;
    int ob = ib + SPLIT1;
    int nout = 0;
    cols[ob] = i; vals[ob] = bii * bii; nout = 1;
    for (int a = 0; a < n; a++) {
      int k = cols[ib + a];
      if (k == i) continue;
      float dk = dinv[k];
      float bik = 0.8f * di * vals[ib + a] * dk;
      float bkk = 0.8f * dk * dk * sval[k];
      if (nout < MAXD2) { cols[ob + nout] = k; vals[ob + nout] = bik * (bii + bkk); nout++; }
      int nk = nnz[k];
      int kb = k * MAXDEG;
      for (int b = 0; b < nk; b++) {
        int g = cols[kb + b];
        if (g == k) continue;
        float bkg = 0.8f * dk * vals[kb + b] * dinv[g];
        if (nout < MAXD2) { cols[ob + nout] = g; vals[ob + nout] = bik * bkg; nout++; }
      }
    }
    nnz2[i] = nout;
    return;
  }

  // ---------------- gg path: wave per row ----------------
  int wave = t >> 6, lane = t & 63;
  int row = blockIdx.x * 4 + wave;
  int n = nnz[row];
  int base = row * MAXDEG;

  u16x4 h0v = *(const u16x4*)&hb0[(size_t)row * HID + lane * 4];
  int4   cv = *(const int4*)&cols[base];
  float4 vv = *(const float4*)&vals[base];

  int jj[4]; float ww[4];
  jj[0] = (0 < n) ? cv.x : row;  ww[0] = (0 < n) ? vv.x : 0.f;
  jj[1] = (1 < n) ? cv.y : row;  ww[1] = (1 < n) ? vv.y : 0.f;
  jj[2] = (2 < n) ? cv.z : row;  ww[2] = (2 < n) ? vv.z : 0.f;
  jj[3] = (3 < n) ? cv.w : row;  ww[3] = (3 < n) ? vv.w : 0.f;

  float ax = 0.f, ay = 0.f, az = 0.f, aw = 0.f;
#pragma unroll
  for (int k = 0; k < 4; k++) {
    float wgt = ww[k] * dinv[jj[k]];
    u16x4 hv = *(const u16x4*)&hb0[(size_t)jj[k] * HID + lane * 4];
    ax += wgt * bf2f(hv[0]); ay += wgt * bf2f(hv[1]);
    az += wgt * bf2f(hv[2]); aw += wgt * bf2f(hv[3]);
  }
  for (int k = 4; k < n; k++) {
    int j = cols[base + k];
    float wgt = vals[base + k] * dinv[j];
    u16x4 hv = *(const u16x4*)&hb0[(size_t)j * HID + lane * 4];
    ax += wgt * bf2f(hv[0]); ay += wgt * bf2f(hv[1]);
    az += wgt * bf2f(hv[2]); aw += wgt * bf2f(hv[3]);
  }
  float s = 0.16f * dinv[row];   // 0.2 * 0.8*dinv
  u16x4 o;
  o[0] = f2bf(s * ax + 0.2f * bf2f(h0v[0]));
  o[1] = f2bf(s * ay + 0.2f * bf2f(h0v[1]));
  o[2] = f2bf(s * az + 0.2f * bf2f(h0v[2]));
  o[3] = f2bf(s * aw + 0.2f * bf2f(h0v[3]));
  *(u16x4*)&hbg[(size_t)row * HID + lane * 4] = o;
}

// ---------------------------------------------------------------------------
// pair: one DOUBLE APPNP step:  h_out = B^2 h_in + gg.  Weights pre-folded;
// wave per row; <=4 fast path + 4-wide unrolled tail (root ~80 entries).
// ---------------------------------------------------------------------------
template <int FINAL>
__global__ __launch_bounds__(256) void pair_step(
    const unsigned short* __restrict__ h_in, const unsigned short* __restrict__ hbg,
    void* __restrict__ h_out_v, const int* __restrict__ nnz2,
    const int* __restrict__ cols, const float* __restrict__ vals) {
  int wave = threadIdx.x >> 6;
  int lane = threadIdx.x & 63;
  int row = blockIdx.x * 4 + wave;

  int n2 = nnz2[row];
  int base2 = row * MAXDEG + SPLIT1;

  u16x4 ggv = *(const u16x4*)&hbg[(size_t)row * HID + lane * 4];
  int4   cv = *(const int4*)&cols[base2];
  float4 vv = *(const float4*)&vals[base2];

  int jj[4]; float ww[4];
  jj[0] = (0 < n2) ? cv.x : row;  ww[0] = (0 < n2) ? vv.x : 0.f;
  jj[1] = (1 < n2) ? cv.y : row;  ww[1] = (1 < n2) ? vv.y : 0.f;
  jj[2] = (2 < n2) ? cv.z : row;  ww[2] = (2 < n2) ? vv.z : 0.f;
  jj[3] = (3 < n2) ? cv.w : row;  ww[3] = (3 < n2) ? vv.w : 0.f;

  float ax = 0.f, ay = 0.f, az = 0.f, aw = 0.f;
#pragma unroll
  for (int k = 0; k < 4; k++) {
    float wgt = ww[k];
    u16x4 hv = *(const u16x4*)&h_in[(size_t)jj[k] * HID + lane * 4];
    ax += wgt * bf2f(hv[0]); ay += wgt * bf2f(hv[1]);
    az += wgt * bf2f(hv[2]); aw += wgt * bf2f(hv[3]);
  }
  for (int k0 = 4; k0 < n2; k0 += 4) {   // 4-wide unrolled tail
    int tj[4]; float tw[4];
#pragma unroll
    for (int e = 0; e < 4; e++) {
      int idx = k0 + e;
      tj[e] = (idx < n2) ? cols[base2 + idx] : row;
      tw[e] = (idx < n2) ? vals[base2 + idx] : 0.f;
    }
#pragma unroll
    for (int e = 0; e < 4; e++) {
      u16x4 hv = *(const u16x4*)&h_in[(size_t)tj[e] * HID + lane * 4];
      ax += tw[e] * bf2f(hv[0]); ay += tw[e] * bf2f(hv[1]);
      az += tw[e] * bf2f(hv[2]); aw += tw[e] * bf2f(hv[3]);
    }
  }

  if (FINAL) {
    float4 o;
    o.x = ax + bf2f(ggv[0]);
    o.y = ay + bf2f(ggv[1]);
    o.z = az + bf2f(ggv[2]);
    o.w = aw + bf2f(ggv[3]);
    *(float4*)&((float*)h_out_v)[(size_t)row * HID + lane * 4] = o;
  } else {
    u16x4 o;
    o[0] = f2bf(ax + bf2f(ggv[0]));
    o[1] = f2bf(ay + bf2f(ggv[1]));
    o[2] = f2bf(az + bf2f(ggv[2]));
    o[3] = f2bf(aw + bf2f(ggv[3]));
    *(u16x4*)&((unsigned short*)h_out_v)[(size_t)row * HID + lane * 4] = o;
  }
}

// ---------------------------------------------------------------------------
extern "C" void kernel_launch(void* const* d_in, const int* in_sizes, int n_in,
                              void* d_out, int out_size, void* d_ws, size_t ws_size,
                              hipStream_t stream) {
  const float* X    = (const float*)d_in[0];  // [8192,1024]
  const float* W    = (const float*)d_in[1];  // [1024,256]
  const float* bias = (const float*)d_in[2];  // [256]
  const float* adj  = (const float*)d_in[3];  // [8192,8192]
  float* out = (float*)d_out;                 // [8192,256]

  char* ws = (char*)d_ws;
  unsigned short* hb0 = (unsigned short*)(ws);                            // 4 MB
  unsigned short* hb1 = (unsigned short*)(ws + (size_t)4 * 1024 * 1024);  // 4 MB
  unsigned short* hb2 = (unsigned short*)(ws + (size_t)8 * 1024 * 1024);  // 4 MB
  unsigned short* hbg = (unsigned short*)(ws + (size_t)12 * 1024 * 1024); // 4 MB
  float* dinv = (float*)(ws + (size_t)16 * 1024 * 1024);                  // 32 KB
  int*   nnz  = (int*)  (ws + (size_t)16 * 1024 * 1024 + 32 * 1024);      // 32 KB
  float* sval = (float*)(ws + (size_t)16 * 1024 * 1024 + 64 * 1024);      // 32 KB
  int*   nnz2 = (int*)  (ws + (size_t)16 * 1024 * 1024 + 96 * 1024);      // 32 KB
  int*   cols = (int*)  (ws + (size_t)16 * 1024 * 1024 + 128 * 1024);     // 4 MB
  float* vals = (float*)(ws + (size_t)20 * 1024 * 1024 + 128 * 1024);     // 4 MB
  unsigned short* Wt = (unsigned short*)(ws + (size_t)24 * 1024 * 1024
                                            + 128 * 1024);                // 512 KB

  prep_wt<<<64, 256, 0, stream>>>(W, Wt);
  fused_extract_gemm<<<GEMM_BLOCKS + NNODES, 256, 0, stream>>>(
      X, Wt, bias, adj, hb0, dinv, nnz, cols, vals, sval);
  ggbuild<<<GG_BLOCKS + NNODES / 256, 256, 0, stream>>>(
      hb0, hbg, dinv, sval, nnz, cols, vals, nnz2);

  // h2 = B^2 h0 + gg ; h4 = B^2 h2 + gg ; h6 = B^2 h4 + gg (f32 -> out)
  pair_step<0><<<NNODES / 4, 256, 0, stream>>>(hb0, hbg, hb1, nnz2, cols, vals);
  pair_step<0><<<NNODES / 4, 256, 0, stream>>>(hb1, hbg, hb2, nnz2, cols, vals);
  pair_step<1><<<NNODES / 4, 256, 0, stream>>>(hb2, hbg, out, nnz2, cols, vals);
}

// Round 19
// 117.083 us; speedup vs baseline: 1.4833x; 1.4833x over previous
//
#include <hip/hip_runtime.h>
#include <hip/hip_bf16.h>

#define NNODES 8192
#define EMB    1024
#define HID    256
#define MAXDEG 128

typedef float f32x4 __attribute__((ext_vector_type(4)));
typedef short bf16x8v __attribute__((ext_vector_type(8)));
typedef unsigned short u16x4 __attribute__((ext_vector_type(4)));
typedef unsigned short u16x8 __attribute__((ext_vector_type(8)));

static __device__ __forceinline__ unsigned short f2bf(float f) {
  union { float f; unsigned int u; } x; x.f = f;
  unsigned int r = (x.u + 0x7fffu + ((x.u >> 16) & 1u)) >> 16;
  return (unsigned short)r;
}
static __device__ __forceinline__ float bf2f(unsigned short u) {
  union { unsigned int u; float f; } x; x.u = ((unsigned int)u) << 16;
  return x.f;
}

// ---------------------------------------------------------------------------
// Prep: Wt[n][k] = bf16(W[k][n]).  (R15 verbatim)
// ---------------------------------------------------------------------------
__global__ __launch_bounds__(256) void prep_wt(const float* __restrict__ W,
                                               unsigned short* __restrict__ Wt) {
  __shared__ float lds[64 * 65];
  int k0 = (blockIdx.x >> 2) * 64;
  int n0 = (blockIdx.x & 3) * 64;
  int t = threadIdx.x;
#pragma unroll
  for (int p = 0; p < 4; p++) {
    int k = p * 16 + (t >> 4);
    int c4 = (t & 15) * 4;
    float4 v = *(const float4*)&W[(size_t)(k0 + k) * HID + n0 + c4];
    lds[k * 65 + c4 + 0] = v.x; lds[k * 65 + c4 + 1] = v.y;
    lds[k * 65 + c4 + 2] = v.z; lds[k * 65 + c4 + 3] = v.w;
  }
  __syncthreads();
  int n = t >> 2, kq = t & 3;
  u16x8 o0, o1;
#pragma unroll
  for (int i = 0; i < 8; i++) o0[i] = f2bf(lds[(kq * 16 + i) * 65 + n]);
#pragma unroll
  for (int i = 0; i < 8; i++) o1[i] = f2bf(lds[(kq * 16 + 8 + i) * 65 + n]);
  unsigned short* dst = &Wt[(size_t)(n0 + n) * EMB + k0 + kq * 16];
  *(u16x8*)(dst) = o0;
  *(u16x8*)(dst + 8) = o1;
}

// ---------------------------------------------------------------------------
// Fused (R15 verbatim): blocks [0,256) = bf16-MFMA GEMM 128x64 tile;
// blocks [256, 256+8192) = extract with 8 batched nontemporal loads.
// ---------------------------------------------------------------------------
#define GEMM_BLOCKS 256

__global__ __launch_bounds__(256) void fused_extract_gemm(
    const float* __restrict__ X, const unsigned short* __restrict__ Wt,
    const float* __restrict__ bias, const float* __restrict__ adj,
    unsigned short* __restrict__ hb0, float* __restrict__ dinv,
    int* __restrict__ nnz, int* __restrict__ cols, float* __restrict__ vals) {
  __shared__ char smem[24 * 1024 + 64];
  int t = threadIdx.x;

  if (blockIdx.x >= GEMM_BLOCKS) {
    // ---------------- extract path ----------------
    int row = blockIdx.x - GEMM_BLOCKS;
    int* s_cnt = (int*)smem;
    float* s_part = (float*)(smem + 16);
    if (t == 0) *s_cnt = 0;
    __syncthreads();
    const f32x4* arow = (const f32x4*)(adj + (size_t)row * NNODES);
    int base = row * MAXDEG;

    f32x4 v[8];
#pragma unroll
    for (int i = 0; i < 8; i++)
      v[i] = __builtin_nontemporal_load(arow + i * 256 + t);

    float sum = 0.f;
#pragma unroll
    for (int i = 0; i < 8; i++) {
      sum += v[i].x + v[i].y + v[i].z + v[i].w;
      int j0 = (i * 256 + t) * 4;
      if (v[i].x != 0.f) { int p = atomicAdd(s_cnt, 1); if (p < MAXDEG) { cols[base + p] = j0 + 0; vals[base + p] = v[i].x; } }
      if (v[i].y != 0.f) { int p = atomicAdd(s_cnt, 1); if (p < MAXDEG) { cols[base + p] = j0 + 1; vals[base + p] = v[i].y; } }
      if (v[i].z != 0.f) { int p = atomicAdd(s_cnt, 1); if (p < MAXDEG) { cols[base + p] = j0 + 2; vals[base + p] = v[i].z; } }
      if (v[i].w != 0.f) { int p = atomicAdd(s_cnt, 1); if (p < MAXDEG) { cols[base + p] = j0 + 3; vals[base + p] = v[i].w; } }
    }
    for (int off = 32; off > 0; off >>= 1) sum += __shfl_down(sum, off, 64);
    int wave = t >> 6;
    if ((t & 63) == 0) s_part[wave] = sum;
    __syncthreads();
    if (t == 0) {
      float tot = s_part[0] + s_part[1] + s_part[2] + s_part[3];
      dinv[row] = rsqrtf(tot);
      int c = *s_cnt;
      nnz[row] = (c > MAXDEG) ? MAXDEG : c;
    }
    return;
  }

  // ---------------- GEMM path: 128x64 tile, BK=64, bf16 MFMA ----------------
  unsigned short* As = (unsigned short*)smem;               // [128][64] bf16
  unsigned short* Bs = (unsigned short*)(smem + 16 * 1024); // [64][64] bf16 (B^T)
  int mb = blockIdx.x >> 2, nb = blockIdx.x & 3;
  int m0 = mb * 128, n0 = nb * 64;
  int w = t >> 6, l = t & 63;

  f32x4 acc[2][4] = {};

  for (int kt = 0; kt < EMB; kt += 64) {
    __syncthreads();
    {
      int c4 = t & 15;
#pragma unroll
      for (int rr = 0; rr < 8; rr++) {
        int row = rr * 16 + (t >> 4);
        float4 v = *(const float4*)&X[(size_t)(m0 + row) * EMB + kt + c4 * 4];
        u16x4 pk = {f2bf(v.x), f2bf(v.y), f2bf(v.z), f2bf(v.w)};
        int slot = ((c4 >> 1) + (row >> 1)) & 7;
        *(u16x4*)&As[row * 64 + slot * 8 + (c4 & 1) * 4] = pk;
      }
    }
    {
      int n = t >> 2, q = t & 3;
      const unsigned short* src = &Wt[(size_t)(n0 + n) * EMB + kt + q * 16];
#pragma unroll
      for (int e = 0; e < 2; e++) {
        u16x8 v = *(const u16x8*)(src + e * 8);
        int slot = ((q * 2 + e) + (n >> 1)) & 7;
        *(u16x8*)&Bs[n * 64 + slot * 8] = v;
      }
    }
    __syncthreads();
#pragma unroll
    for (int ks = 0; ks < 2; ks++) {
      bf16x8v a[2], b[4];
#pragma unroll
      for (int mf = 0; mf < 2; mf++) {
        int row = w * 32 + mf * 16 + (l & 15);
        int slot = ((ks * 4 + (l >> 4)) + (row >> 1)) & 7;
        a[mf] = *(bf16x8v*)&As[row * 64 + slot * 8];
      }
#pragma unroll
      for (int nf = 0; nf < 4; nf++) {
        int rowB = nf * 16 + (l & 15);
        int slot = ((ks * 4 + (l >> 4)) + (rowB >> 1)) & 7;
        b[nf] = *(bf16x8v*)&Bs[rowB * 64 + slot * 8];
      }
#pragma unroll
      for (int mf = 0; mf < 2; mf++)
#pragma unroll
        for (int nf = 0; nf < 4; nf++)
          acc[mf][nf] = __builtin_amdgcn_mfma_f32_16x16x32_bf16(a[mf], b[nf], acc[mf][nf], 0, 0, 0);
    }
  }
#pragma unroll
  for (int mf = 0; mf < 2; mf++)
#pragma unroll
    for (int nf = 0; nf < 4; nf++) {
      int r0 = m0 + w * 32 + mf * 16 + (l >> 4) * 4;
      int cc = n0 + nf * 16 + (l & 15);
      float bv = bias[cc];
#pragma unroll
      for (int r = 0; r < 4; r++)
        hb0[(size_t)(r0 + r) * HID + cc] = f2bf(fmaxf(acc[mf][nf][r] + bv, 0.f));
    }
}

// ---------------------------------------------------------------------------
// One APPNP step; 32 lanes x 16B (u16x8) per row, 2 rows per wave, 8 rows
// per block (grid 1024). Same latency chain as R15 but half the memory
// instructions and full TLP (8 independent row-contexts per block).
// Poison-safe <=4-edge fast path; divergent tail only for rare n>4.
// ---------------------------------------------------------------------------
template <int FINAL>
__global__ __launch_bounds__(256) void prop_step_t(
    const unsigned short* __restrict__ h_in, const unsigned short* __restrict__ hb0,
    void* __restrict__ h_out_v, const float* __restrict__ dinv,
    const int* __restrict__ nnz, const int* __restrict__ cols,
    const float* __restrict__ vals) {
  int t = threadIdx.x;
  int half = t >> 5;      // 0..7 -> row within block
  int lr = t & 31;        // lane within row; features [lr*8, lr*8+8)
  int row = blockIdx.x * 8 + half;

  int n = nnz[row];
  int base = row * MAXDEG;

  u16x8 h0v = *(const u16x8*)&hb0[(size_t)row * HID + lr * 8];
  int4   cv = *(const int4*)&cols[base];
  float4 vv = *(const float4*)&vals[base];

  int jj[4]; float ww[4];
  jj[0] = (0 < n) ? cv.x : row;  ww[0] = (0 < n) ? vv.x : 0.f;
  jj[1] = (1 < n) ? cv.y : row;  ww[1] = (1 < n) ? vv.y : 0.f;
  jj[2] = (2 < n) ? cv.z : row;  ww[2] = (2 < n) ? vv.z : 0.f;
  jj[3] = (3 < n) ? cv.w : row;  ww[3] = (3 < n) ? vv.w : 0.f;

  float acc[8] = {0.f, 0.f, 0.f, 0.f, 0.f, 0.f, 0.f, 0.f};
#pragma unroll
  for (int k = 0; k < 4; k++) {
    float wgt = ww[k] * dinv[jj[k]];
    u16x8 hv = *(const u16x8*)&h_in[(size_t)jj[k] * HID + lr * 8];
#pragma unroll
    for (int e = 0; e < 8; e++) acc[e] += wgt * bf2f(hv[e]);
  }
  for (int k = 4; k < n; k++) {          // rare
    int j = cols[base + k];
    float wgt = vals[base + k] * dinv[j];
    u16x8 hv = *(const u16x8*)&h_in[(size_t)j * HID + lr * 8];
#pragma unroll
    for (int e = 0; e < 8; e++) acc[e] += wgt * bf2f(hv[e]);
  }
  float s = 0.8f * dinv[row];
  if (FINAL) {
    float* outp = &((float*)h_out_v)[(size_t)row * HID + lr * 8];
    float4 o0, o1;
    o0.x = s * acc[0] + 0.2f * bf2f(h0v[0]);
    o0.y = s * acc[1] + 0.2f * bf2f(h0v[1]);
    o0.z = s * acc[2] + 0.2f * bf2f(h0v[2]);
    o0.w = s * acc[3] + 0.2f * bf2f(h0v[3]);
    o1.x = s * acc[4] + 0.2f * bf2f(h0v[4]);
    o1.y = s * acc[5] + 0.2f * bf2f(h0v[5]);
    o1.z = s * acc[6] + 0.2f * bf2f(h0v[6]);
    o1.w = s * acc[7] + 0.2f * bf2f(h0v[7]);
    *(float4*)(outp) = o0;
    *(float4*)(outp + 4) = o1;
  } else {
    u16x8 o;
#pragma unroll
    for (int e = 0; e < 8; e++) o[e] = f2bf(s * acc[e] + 0.2f * bf2f(h0v[e]));
    *(u16x8*)&((unsigned short*)h_out_v)[(size_t)row * HID + lr * 8] = o;
  }
}

// ---------------------------------------------------------------------------
extern "C" void kernel_launch(void* const* d_in, const int* in_sizes, int n_in,
                              void* d_out, int out_size, void* d_ws, size_t ws_size,
                              hipStream_t stream) {
  const float* X    = (const float*)d_in[0];  // [8192,1024]
  const float* W    = (const float*)d_in[1];  // [1024,256]
  const float* bias = (const float*)d_in[2];  // [256]
  const float* adj  = (const float*)d_in[3];  // [8192,8192]
  float* out = (float*)d_out;                 // [8192,256]

  char* ws = (char*)d_ws;
  unsigned short* hb0  = (unsigned short*)(ws);                           // 4 MB
  unsigned short* hb1  = (unsigned short*)(ws + (size_t)4 * 1024 * 1024); // 4 MB
  unsigned short* hb2  = (unsigned short*)(ws + (size_t)8 * 1024 * 1024); // 4 MB
  float* dinv = (float*)(ws + (size_t)12 * 1024 * 1024);                  // 32 KB
  int*   nnz  = (int*)  (ws + (size_t)12 * 1024 * 1024 + 32 * 1024);      // 32 KB
  int*   cols = (int*)  (ws + (size_t)12 * 1024 * 1024 + 64 * 1024);      // 4 MB
  float* vals = (float*)(ws + (size_t)16 * 1024 * 1024 + 64 * 1024);      // 4 MB
  unsigned short* Wt = (unsigned short*)(ws + (size_t)20 * 1024 * 1024
                                            + 64 * 1024);                 // 512 KB

  prep_wt<<<64, 256, 0, stream>>>(W, Wt);
  fused_extract_gemm<<<GEMM_BLOCKS + NNODES, 256, 0, stream>>>(
      X, Wt, bias, adj, hb0, dinv, nnz, cols, vals);

  // 5 bf16 steps ping-ponging hb1/hb2, then final f32 step into d_out.
  prop_step_t<0><<<NNODES / 8, 256, 0, stream>>>(hb0, hb0, hb1, dinv, nnz, cols, vals);
  prop_step_t<0><<<NNODES / 8, 256, 0, stream>>>(hb1, hb0, hb2, dinv, nnz, cols, vals);
  prop_step_t<0><<<NNODES / 8, 256, 0, stream>>>(hb2, hb0, hb1, dinv, nnz, cols, vals);
  prop_step_t<0><<<NNODES / 8, 256, 0, stream>>>(hb1, hb0, hb2, dinv, nnz, cols, vals);
  prop_step_t<0><<<NNODES / 8, 256, 0, stream>>>(hb2, hb0, hb1, dinv, nnz, cols, vals);
  prop_step_t<1><<<NNODES / 8, 256, 0, stream>>>(hb1, hb0, out, dinv, nnz, cols, vals);
}